// Round 4
// baseline (764.601 us; speedup 1.0000x reference)
//
#include <hip/hip_runtime.h>
#include <hip/hip_bf16.h>
#include <math.h>

// Outputs (float32, concatenated): d[N][64] | dist[N][64][400] | pos[N][64][16] | idx[N][64]
// N = 4096, K = 64 neighbors (self first).
// Neighbor ordering follows the f64-exact distances (harness np reference is
// f64); f64 squared-distance bits used as monotone u64 sort keys.

__device__ __constant__ float c_centers[16] = {
  0.0f,
  (float)( 1.0*20.0/15.0), (float)( 2.0*20.0/15.0), (float)( 3.0*20.0/15.0),
  (float)( 4.0*20.0/15.0), (float)( 5.0*20.0/15.0), (float)( 6.0*20.0/15.0),
  (float)( 7.0*20.0/15.0), (float)( 8.0*20.0/15.0), (float)( 9.0*20.0/15.0),
  (float)(10.0*20.0/15.0), (float)(11.0*20.0/15.0), (float)(12.0*20.0/15.0),
  (float)(13.0*20.0/15.0), (float)(14.0*20.0/15.0), (float)(15.0*20.0/15.0)
};
// freq[f] = exp(-(2f) * ln(10000)/16) = 10^(-f/2)
__device__ __constant__ float c_freq[8] = {
  1.0f, 0.31622776601683794f, 0.1f, 0.031622776601683791f,
  0.01f, 0.0031622776601683794f, 0.001f, 0.00031622776601683794f
};

// ---------------- kernel 1: build crd5 = [crd(4 atoms), Cb] ----------------
__global__ __launch_bounds__(256) void crd5_kernel(
    const float* __restrict__ crd, float* __restrict__ crd5, int N) {
  int i = blockIdx.x * 256 + threadIdx.x;
  if (i >= N) return;
  const float* p = crd + (size_t)i * 12;
  float p0x=p[0], p0y=p[1], p0z=p[2];
  float p1x=p[3], p1y=p[4], p1z=p[5];
  float p2x=p[6], p2y=p[7], p2z=p[8];
  float p3x=p[9], p3y=p[10], p3z=p[11];
  float bx=__fsub_rn(p1x,p0x), by=__fsub_rn(p1y,p0y), bz=__fsub_rn(p1z,p0z);
  float cx=__fsub_rn(p2x,p1x), cy=__fsub_rn(p2y,p1y), cz=__fsub_rn(p2z,p1z);
  // a = cross(b, c)
  float ax=__fsub_rn(__fmul_rn(by,cz), __fmul_rn(bz,cy));
  float ay=__fsub_rn(__fmul_rn(bz,cx), __fmul_rn(bx,cz));
  float az=__fsub_rn(__fmul_rn(bx,cy), __fmul_rn(by,cx));
  const float K1 = -0.58273431f, K2 = 0.56802827f, K3 = 0.54067466f;
  float cbx=__fadd_rn(__fsub_rn(__fadd_rn(__fmul_rn(K1,ax),__fmul_rn(K2,bx)),__fmul_rn(K3,cx)),p1x);
  float cby=__fadd_rn(__fsub_rn(__fadd_rn(__fmul_rn(K1,ay),__fmul_rn(K2,by)),__fmul_rn(K3,cy)),p1y);
  float cbz=__fadd_rn(__fsub_rn(__fadd_rn(__fmul_rn(K1,az),__fmul_rn(K2,bz)),__fmul_rn(K3,cz)),p1z);
  float* o = crd5 + (size_t)i * 15;
  o[0]=p0x; o[1]=p0y; o[2]=p0z;
  o[3]=p1x; o[4]=p1y; o[5]=p1z;
  o[6]=p2x; o[7]=p2y; o[8]=p2z;
  o[9]=p3x; o[10]=p3y; o[11]=p3z;
  o[12]=cbx; o[13]=cby; o[14]=cbz;
}

// ---------------- kernel 2: kNN (top-64 smallest f64 distances) ------------
// One 256-thread block per row i. Each thread owns 16 candidate j's
// (j = tid + s*256). Keys are f64 squared-distance bit patterns (monotone
// u64 for non-negative doubles); ties (impossible in f64 for distinct random
// points) would break by lower index, matching lax.top_k.
__global__ __launch_bounds__(256) void knn_kernel(
    const float* __restrict__ crd,
    float* __restrict__ out_d,
    float* __restrict__ out_pos,
    float* __restrict__ out_idx,
    int* __restrict__ idx_ws,
    int N) {
  const int i = blockIdx.x;
  const int t = threadIdx.x;

  __shared__ unsigned long long s_key[64];
  __shared__ int                s_idx[64];
  __shared__ unsigned long long s_wk[4];
  __shared__ int                s_wj[4];

  const double cix = (double)crd[(size_t)i*12 + 3];
  const double ciy = (double)crd[(size_t)i*12 + 4];
  const double ciz = (double)crd[(size_t)i*12 + 5];

  const unsigned long long INVALID = 0xFFFFFFFFFFFFFFFFull;

  unsigned long long key[16];
  #pragma unroll
  for (int s = 0; s < 16; ++s) {
    int j = t + s * 256;
    unsigned long long kk = INVALID;
    if (j < N && j != i) {
      double dx = cix - (double)crd[(size_t)j*12 + 3];
      double dy = ciy - (double)crd[(size_t)j*12 + 4];
      double dz = ciz - (double)crd[(size_t)j*12 + 5];
      double sq = dx*dx + dy*dy + dz*dz;
      kk = (unsigned long long)__double_as_longlong(sq);
    }
    key[s] = kk;
  }

  if (t == 0) { s_key[0] = 0ull; s_idx[0] = i; }  // self first, d = 0

  for (int k = 1; k < 64; ++k) {
    // local min over 16 regs (ascending s => ascending j; strict < keeps lowest j)
    unsigned long long bk = key[0]; int bs = 0;
    #pragma unroll
    for (int s = 1; s < 16; ++s) {
      if (key[s] < bk) { bk = key[s]; bs = s; }
    }
    int bj = t + bs * 256;
    // wave reduce (64 lanes), lexicographic (key, idx)
    #pragma unroll
    for (int o = 32; o > 0; o >>= 1) {
      unsigned long long ok = __shfl_xor(bk, o, 64);
      int                oj = __shfl_xor(bj, o, 64);
      if (ok < bk || (ok == bk && oj < bj)) { bk = ok; bj = oj; }
    }
    int wid = t >> 6;
    if ((t & 63) == 0) { s_wk[wid] = bk; s_wj[wid] = bj; }
    __syncthreads();
    unsigned long long selk = s_wk[0]; int selj = s_wj[0];
    #pragma unroll
    for (int w = 1; w < 4; ++w) {
      unsigned long long wk = s_wk[w]; int wj = s_wj[w];
      if (wk < selk || (wk == selk && wj < selj)) { selk = wk; selj = wj; }
    }
    if (t == 0) { s_key[k] = selk; s_idx[k] = selj; }
    // owner removes the selected candidate
    if ((selj & 255) == t) {
      int cs = selj >> 8;
      #pragma unroll
      for (int s = 0; s < 16; ++s) if (s == cs) key[s] = INVALID;
    }
    __syncthreads();
  }

  if (t < 64) {
    double sq = __longlong_as_double((long long)s_key[t]);
    int    j  = s_idx[t];
    size_t base = (size_t)i * 64 + t;
    out_d[base]   = (float)sqrt(sq);
    out_idx[base] = (float)j;
    idx_ws[base]  = j;
    int off = i - j; if (off < 0) off = -off;
    float offf = (float)off;
    float* pp = out_pos + base * 16;
    #pragma unroll
    for (int f = 0; f < 8; ++f) {
      float ang = offf * c_freq[f];
      pp[f]     = cosf(ang);
      pp[8 + f] = sinf(ang);
    }
  }
}

// ---------------- kernel 3: grbf distance features ------------------------
// One wave per (i,k) pair; 4 pairs per 256-thread block.
__global__ __launch_bounds__(256) void feat_kernel(
    const float* __restrict__ crd5,
    const int* __restrict__ idx_ws,
    float* __restrict__ out_dist,
    int N) {
  const int w = threadIdx.x >> 6;
  const int lane = threadIdx.x & 63;
  const size_t g = (size_t)blockIdx.x * 4 + w;   // pair id in [0, N*64)
  const int i = (int)(g >> 6);

  __shared__ float sd[4][25];

  const int nj = idx_ws[g];
  if (lane < 25) {
    const int p = lane / 5, q = lane % 5;
    const float* A = crd5 + (size_t)i * 15 + p * 3;
    const float* B = crd5 + (size_t)nj * 15 + q * 3;
    float dx = A[0] - B[0];
    float dy = A[1] - B[1];
    float dz = A[2] - B[2];
    sd[w][lane] = sqrtf(dx*dx + dy*dy + dz*dz);
  }
  __syncthreads();

  float* o = out_dist + g * 400;
  #pragma unroll
  for (int r = 0; r < 7; ++r) {
    int oo = lane + r * 64;
    if (oo < 400) {
      float dd = sd[w][oo >> 4];
      float x = dd - c_centers[oo & 15];
      o[oo] = __expf(-x * x);
    }
  }
}

// ---------------- launcher ------------------------------------------------
extern "C" void kernel_launch(void* const* d_in, const int* in_sizes, int n_in,
                              void* d_out, int out_size, void* d_ws, size_t ws_size,
                              hipStream_t stream) {
  const float* crd = (const float*)d_in[0];
  const int N = in_sizes[0] / 12;        // 4096
  const size_t NK = (size_t)N * 64;

  // workspace: [ idx int NK | crd5 float N*15 ]
  int*   idx_ws = (int*)d_ws;
  float* crd5   = (float*)((char*)d_ws + NK * sizeof(int));

  float* out = (float*)d_out;
  float* out_d    = out;
  float* out_dist = out + NK;
  float* out_pos  = out + NK + NK * 400;
  float* out_idx  = out + NK + NK * 400 + NK * 16;

  crd5_kernel<<<(N + 255) / 256, 256, 0, stream>>>(crd, crd5, N);
  knn_kernel<<<N, 256, 0, stream>>>(crd, out_d, out_pos, out_idx, idx_ws, N);
  feat_kernel<<<N * 16, 256, 0, stream>>>(crd5, idx_ws, out_dist, N);
}

// Round 5
// 704.409 us; speedup vs baseline: 1.0854x; 1.0854x over previous
//
#include <hip/hip_runtime.h>
#include <hip/hip_bf16.h>
#include <math.h>

// Outputs (float32, concatenated): d[N][64] | dist[N][64][400] | pos[N][64][16] | idx[N][64]
// N = 4096, K = 64 neighbors (self first).
// Neighbor ordering follows the f64-exact distances (harness np reference is
// f64); f64 squared-distance bits used as monotone u64 sort keys.

// freq[f] = exp(-(2f) * ln(10000)/16) = 10^(-f/2)
__device__ __constant__ float c_freq[8] = {
  1.0f, 0.31622776601683794f, 0.1f, 0.031622776601683791f,
  0.01f, 0.0031622776601683794f, 0.001f, 0.00031622776601683794f
};

// ---------------- kernel 1: build crd5 = [crd(4 atoms), Cb] ----------------
__global__ __launch_bounds__(256) void crd5_kernel(
    const float* __restrict__ crd, float* __restrict__ crd5, int N) {
  int i = blockIdx.x * 256 + threadIdx.x;
  if (i >= N) return;
  const float* p = crd + (size_t)i * 12;
  float p0x=p[0], p0y=p[1], p0z=p[2];
  float p1x=p[3], p1y=p[4], p1z=p[5];
  float p2x=p[6], p2y=p[7], p2z=p[8];
  float p3x=p[9], p3y=p[10], p3z=p[11];
  float bx=__fsub_rn(p1x,p0x), by=__fsub_rn(p1y,p0y), bz=__fsub_rn(p1z,p0z);
  float cx=__fsub_rn(p2x,p1x), cy=__fsub_rn(p2y,p1y), cz=__fsub_rn(p2z,p1z);
  float ax=__fsub_rn(__fmul_rn(by,cz), __fmul_rn(bz,cy));
  float ay=__fsub_rn(__fmul_rn(bz,cx), __fmul_rn(bx,cz));
  float az=__fsub_rn(__fmul_rn(bx,cy), __fmul_rn(by,cx));
  const float K1 = -0.58273431f, K2 = 0.56802827f, K3 = 0.54067466f;
  float cbx=__fadd_rn(__fsub_rn(__fadd_rn(__fmul_rn(K1,ax),__fmul_rn(K2,bx)),__fmul_rn(K3,cx)),p1x);
  float cby=__fadd_rn(__fsub_rn(__fadd_rn(__fmul_rn(K1,ay),__fmul_rn(K2,by)),__fmul_rn(K3,cy)),p1y);
  float cbz=__fadd_rn(__fsub_rn(__fadd_rn(__fmul_rn(K1,az),__fmul_rn(K2,bz)),__fmul_rn(K3,cz)),p1z);
  float* o = crd5 + (size_t)i * 15;
  o[0]=p0x; o[1]=p0y; o[2]=p0z;
  o[3]=p1x; o[4]=p1y; o[5]=p1z;
  o[6]=p2x; o[7]=p2y; o[8]=p2z;
  o[9]=p3x; o[10]=p3y; o[11]=p3z;
  o[12]=cbx; o[13]=cby; o[14]=cbz;
}

// ---------------- kernel 2: kNN (top-64 smallest f64 distances) ------------
// One 256-thread block per row i; thread t owns candidates j = t + s*256.
// Cached-argmin: per-thread local min (lk,lj) and per-wave winner (wwk,wwj)
// live in registers; per round only the owner thread rescans its 16 keys and
// only the owner's wave re-reduces. Wave winners are double-buffered in LDS
// so each round needs a single __syncthreads.
__global__ __launch_bounds__(256) void knn_kernel(
    const float* __restrict__ crd,
    float* __restrict__ out_d,
    float* __restrict__ out_pos,
    float* __restrict__ out_idx,
    int* __restrict__ idx_ws,
    int N) {
  const int i = blockIdx.x;
  const int t = threadIdx.x;
  const int wid = t >> 6;

  __shared__ unsigned long long s_wk[2][4];
  __shared__ int                s_wj[2][4];
  __shared__ unsigned long long s_key[64];
  __shared__ int                s_idx[64];

  const double cix = (double)crd[(size_t)i*12 + 3];
  const double ciy = (double)crd[(size_t)i*12 + 4];
  const double ciz = (double)crd[(size_t)i*12 + 5];

  const unsigned long long INVALID = 0xFFFFFFFFFFFFFFFFull;

  unsigned long long key[16];
  #pragma unroll
  for (int s = 0; s < 16; ++s) {
    int j = t + s * 256;
    unsigned long long kk = INVALID;
    if (j < N && j != i) {
      double dx = cix - (double)crd[(size_t)j*12 + 3];
      double dy = ciy - (double)crd[(size_t)j*12 + 4];
      double dz = ciz - (double)crd[(size_t)j*12 + 5];
      double sq = dx*dx + dy*dy + dz*dz;
      kk = (unsigned long long)__double_as_longlong(sq);
    }
    key[s] = kk;
  }

  // cached per-thread local min
  unsigned long long lk; int lj;
  {
    unsigned long long mk = key[0]; int ms = 0;
    #pragma unroll
    for (int s = 1; s < 16; ++s) if (key[s] < mk) { mk = key[s]; ms = s; }
    lk = mk; lj = t + ms * 256;
  }
  // cached per-wave winner (butterfly leaves result in all lanes)
  unsigned long long wwk; int wwj;
  {
    unsigned long long rk = lk; int rj = lj;
    #pragma unroll
    for (int o = 32; o > 0; o >>= 1) {
      unsigned long long ok = __shfl_xor(rk, o, 64);
      int                oj = __shfl_xor(rj, o, 64);
      if (ok < rk || (ok == rk && oj < rj)) { rk = ok; rj = oj; }
    }
    wwk = rk; wwj = rj;
  }
  if ((t & 63) == 0) { s_wk[0][wid] = wwk; s_wj[0][wid] = wwj; }
  if (t == 0) { s_key[0] = 0ull; s_idx[0] = i; }  // self first, d = 0
  __syncthreads();

  for (int k = 1; k < 64; ++k) {
    const int b = (k - 1) & 1;
    // global winner from 4 cached wave winners (all threads)
    unsigned long long selk = s_wk[b][0]; int selj = s_wj[b][0];
    #pragma unroll
    for (int w = 1; w < 4; ++w) {
      unsigned long long wk2 = s_wk[b][w]; int wj2 = s_wj[b][w];
      if (wk2 < selk || (wk2 == selk && wj2 < selj)) { selk = wk2; selj = wj2; }
    }
    if (t == 0) { s_key[k] = selk; s_idx[k] = selj; }
    const int ot = selj & 255;
    // owner thread removes winner and rescans its 16 keys
    if (t == ot) {
      const int cs = selj >> 8;
      #pragma unroll
      for (int s = 0; s < 16; ++s) if (s == cs) key[s] = INVALID;
      unsigned long long mk = key[0]; int ms = 0;
      #pragma unroll
      for (int s = 1; s < 16; ++s) if (key[s] < mk) { mk = key[s]; ms = s; }
      lk = mk; lj = t + ms * 256;
    }
    // owner's wave re-reduces; other waves keep cached winner
    if (wid == (ot >> 6)) {
      unsigned long long rk = lk; int rj = lj;
      #pragma unroll
      for (int o = 32; o > 0; o >>= 1) {
        unsigned long long ok = __shfl_xor(rk, o, 64);
        int                oj = __shfl_xor(rj, o, 64);
        if (ok < rk || (ok == rk && oj < rj)) { rk = ok; rj = oj; }
      }
      wwk = rk; wwj = rj;
    }
    // every wave republishes its register winner into the other buffer
    if ((t & 63) == 0) { s_wk[b ^ 1][wid] = wwk; s_wj[b ^ 1][wid] = wwj; }
    __syncthreads();
  }

  if (t < 64) {
    double sq = __longlong_as_double((long long)s_key[t]);
    int    j  = s_idx[t];
    size_t base = (size_t)i * 64 + t;
    out_d[base]   = (float)sqrt(sq);
    out_idx[base] = (float)j;
    idx_ws[base]  = j;
    int off = i - j; if (off < 0) off = -off;
    float offf = (float)off;
    float* pp = out_pos + base * 16;
    #pragma unroll
    for (int f = 0; f < 8; ++f) {
      float ang = offf * c_freq[f];
      pp[f]     = cosf(ang);
      pp[8 + f] = sinf(ang);
    }
  }
}

// ---------------- kernel 3: grbf distance features ------------------------
// One wave per (i,k) pair; 4 pairs per 256-thread block. float4 stores:
// 100 x 16B per pair (64 slots pass 1, 36 slots pass 2).
__global__ __launch_bounds__(256) void feat_kernel(
    const float* __restrict__ crd5,
    const int* __restrict__ idx_ws,
    float* __restrict__ out_dist,
    int N) {
  const int w = threadIdx.x >> 6;
  const int lane = threadIdx.x & 63;
  const size_t g = (size_t)blockIdx.x * 4 + w;   // pair id in [0, N*64)
  const int i = (int)(g >> 6);

  __shared__ float sd[4][26];

  const int nj = idx_ws[g];
  if (lane < 25) {
    const int p = lane / 5, q = lane % 5;
    const float* A = crd5 + (size_t)i * 15 + p * 3;
    const float* B = crd5 + (size_t)nj * 15 + q * 3;
    float dx = A[0] - B[0];
    float dy = A[1] - B[1];
    float dz = A[2] - B[2];
    sd[w][lane] = sqrtf(dx*dx + dy*dy + dz*dz);
  }
  __syncthreads();

  const float SC = 20.0f / 15.0f;   // grbf center spacing
  float4* o = (float4*)(out_dist + g * 400);
  {
    // pass 1: float4 slot = lane (elements 4*lane .. 4*lane+3)
    float dd = sd[w][lane >> 2];
    float c0 = (float)((lane & 3) * 4) * SC;
    float x0 = dd - c0;                 float x1 = dd - (c0 + SC);
    float x2 = dd - (c0 + 2.0f * SC);   float x3 = dd - (c0 + 3.0f * SC);
    float4 r;
    r.x = __expf(-x0 * x0); r.y = __expf(-x1 * x1);
    r.z = __expf(-x2 * x2); r.w = __expf(-x3 * x3);
    o[lane] = r;
  }
  if (lane < 36) {
    // pass 2: float4 slot = 64 + lane (elements 256 + 4*lane ...)
    float dd = sd[w][16 + (lane >> 2)];
    float c0 = (float)((lane & 3) * 4) * SC;
    float x0 = dd - c0;                 float x1 = dd - (c0 + SC);
    float x2 = dd - (c0 + 2.0f * SC);   float x3 = dd - (c0 + 3.0f * SC);
    float4 r;
    r.x = __expf(-x0 * x0); r.y = __expf(-x1 * x1);
    r.z = __expf(-x2 * x2); r.w = __expf(-x3 * x3);
    o[64 + lane] = r;
  }
}

// ---------------- launcher ------------------------------------------------
extern "C" void kernel_launch(void* const* d_in, const int* in_sizes, int n_in,
                              void* d_out, int out_size, void* d_ws, size_t ws_size,
                              hipStream_t stream) {
  const float* crd = (const float*)d_in[0];
  const int N = in_sizes[0] / 12;        // 4096
  const size_t NK = (size_t)N * 64;

  // workspace: [ idx int NK | crd5 float N*15 ]
  int*   idx_ws = (int*)d_ws;
  float* crd5   = (float*)((char*)d_ws + NK * sizeof(int));

  float* out = (float*)d_out;
  float* out_d    = out;
  float* out_dist = out + NK;
  float* out_pos  = out + NK + NK * 400;
  float* out_idx  = out + NK + NK * 400 + NK * 16;

  crd5_kernel<<<(N + 255) / 256, 256, 0, stream>>>(crd, crd5, N);
  knn_kernel<<<N, 256, 0, stream>>>(crd, out_d, out_pos, out_idx, idx_ws, N);
  feat_kernel<<<N * 16, 256, 0, stream>>>(crd5, idx_ws, out_dist, N);
}

// Round 6
// 628.064 us; speedup vs baseline: 1.2174x; 1.1216x over previous
//
#include <hip/hip_runtime.h>
#include <hip/hip_bf16.h>
#include <math.h>

// Outputs (float32, concatenated): d[N][64] | dist[N][64][400] | pos[N][64][16] | idx[N][64]
// N = 4096, K = 64 neighbors (self first). Ordering follows f64-exact
// squared distances (monotone u64 bit keys), tie-break lower index.

// freq[f] = 10^(-f/2)
__device__ __constant__ float c_freq[8] = {
  1.0f, 0.31622776601683794f, 0.1f, 0.031622776601683791f,
  0.01f, 0.0031622776601683794f, 0.001f, 0.00031622776601683794f
};

// ---------------- kernel 1: build crd5 = [crd(4 atoms), Cb] ----------------
__global__ __launch_bounds__(256) void crd5_kernel(
    const float* __restrict__ crd, float* __restrict__ crd5, int N) {
  int i = blockIdx.x * 256 + threadIdx.x;
  if (i >= N) return;
  const float* p = crd + (size_t)i * 12;
  float p0x=p[0], p0y=p[1], p0z=p[2];
  float p1x=p[3], p1y=p[4], p1z=p[5];
  float p2x=p[6], p2y=p[7], p2z=p[8];
  float p3x=p[9], p3y=p[10], p3z=p[11];
  float bx=__fsub_rn(p1x,p0x), by=__fsub_rn(p1y,p0y), bz=__fsub_rn(p1z,p0z);
  float cx=__fsub_rn(p2x,p1x), cy=__fsub_rn(p2y,p1y), cz=__fsub_rn(p2z,p1z);
  float ax=__fsub_rn(__fmul_rn(by,cz), __fmul_rn(bz,cy));
  float ay=__fsub_rn(__fmul_rn(bz,cx), __fmul_rn(bx,cz));
  float az=__fsub_rn(__fmul_rn(bx,cy), __fmul_rn(by,cx));
  const float K1 = -0.58273431f, K2 = 0.56802827f, K3 = 0.54067466f;
  float cbx=__fadd_rn(__fsub_rn(__fadd_rn(__fmul_rn(K1,ax),__fmul_rn(K2,bx)),__fmul_rn(K3,cx)),p1x);
  float cby=__fadd_rn(__fsub_rn(__fadd_rn(__fmul_rn(K1,ay),__fmul_rn(K2,by)),__fmul_rn(K3,cy)),p1y);
  float cbz=__fadd_rn(__fsub_rn(__fadd_rn(__fmul_rn(K1,az),__fmul_rn(K2,bz)),__fmul_rn(K3,cz)),p1z);
  float* o = crd5 + (size_t)i * 15;
  o[0]=p0x; o[1]=p0y; o[2]=p0z;
  o[3]=p1x; o[4]=p1y; o[5]=p1z;
  o[6]=p2x; o[7]=p2y; o[8]=p2z;
  o[9]=p3x; o[10]=p3y; o[11]=p3z;
  o[12]=cbx; o[13]=cby; o[14]=cbz;
}

// ---------------- kernel 2: kNN via radix-select on u64 keys ---------------
// One 256-thread block per row i; thread t owns candidates j = t + s*256.
// 1-3 histogram passes (8 bits each, high->low) locate the bucket holding the
// 63rd-smallest non-self key; all keys at-or-below that bucket (<=318 of them,
// buffer 320) are collected to LDS; wave 0 extracts 63 sorted winners with a
// barrier-free argmin loop; selection order identical to lax.top_k.
__global__ __launch_bounds__(256) void knn_kernel(
    const float* __restrict__ crd,
    float* __restrict__ out_d,
    float* __restrict__ out_pos,
    float* __restrict__ out_idx,
    int* __restrict__ idx_ws,
    int N) {
  const int i = blockIdx.x;
  const int t = threadIdx.x;

  __shared__ unsigned int s_hist[8][256];     // pass-0 sub-histograms
  __shared__ unsigned int s_pref[257];
  __shared__ unsigned int s_info[4];          // [0]=bucket [1]=pref [2]=cnt [3]=cand count
  __shared__ unsigned long long s_ck[320];
  __shared__ int                s_cj[320];

  const unsigned long long INVALID = 0xFFFFFFFFFFFFFFFFull;

  const double cix = (double)crd[(size_t)i*12 + 3];
  const double ciy = (double)crd[(size_t)i*12 + 4];
  const double ciz = (double)crd[(size_t)i*12 + 5];

  unsigned long long key[16];
  #pragma unroll
  for (int s = 0; s < 16; ++s) {
    int j = t + s * 256;
    unsigned long long kk = INVALID;
    if (j < N && j != i) {
      double dx = cix - (double)crd[(size_t)j*12 + 3];
      double dy = ciy - (double)crd[(size_t)j*12 + 4];
      double dz = ciz - (double)crd[(size_t)j*12 + 5];
      double sq = dx*dx + dy*dy + dz*dz;
      kk = (unsigned long long)__double_as_longlong(sq);
    }
    key[s] = kk;
  }

  // ---- radix passes: find bucket containing rank-62 (0-based) non-self key
  unsigned int TR = 62;          // target rank among remaining
  unsigned int prefVal = 0;      // bucket path value
  int shift = 56;                // shift of current pass
  int cshift = 56;               // shift at which prefVal is expressed

  #pragma unroll 1
  for (int pass = 0; pass < 3; ++pass) {
    // zero histograms
    if (pass == 0) {
      unsigned int* h = &s_hist[0][0];
      #pragma unroll
      for (int z = 0; z < 8; ++z) h[t + z * 256] = 0u;
    } else {
      if (t < 256) s_hist[0][t] = 0u;
    }
    __syncthreads();
    // accumulate
    if (pass == 0) {
      unsigned int* h = s_hist[t >> 5];
      #pragma unroll
      for (int s = 0; s < 16; ++s)
        if (key[s] != INVALID) atomicAdd(&h[(unsigned int)(key[s] >> 56)], 1u);
    } else {
      #pragma unroll
      for (int s = 0; s < 16; ++s)
        if ((unsigned int)(key[s] >> (shift + 8)) == prefVal)
          atomicAdd(&s_hist[0][(unsigned int)(key[s] >> shift) & 255u], 1u);
    }
    __syncthreads();
    if (pass == 0) {
      if (t < 256) {
        unsigned int v = 0;
        #pragma unroll
        for (int g = 0; g < 8; ++g) v += s_hist[g][t];
        s_hist[0][t] = v;
      }
      __syncthreads();
    }
    // exclusive prefix over 256 bins (wave 0)
    if (t < 64) {
      unsigned int b0 = s_hist[0][4*t], b1 = s_hist[0][4*t+1];
      unsigned int b2 = s_hist[0][4*t+2], b3 = s_hist[0][4*t+3];
      unsigned int sum = b0 + b1 + b2 + b3;
      unsigned int incl = sum;
      #pragma unroll
      for (int d = 1; d < 64; d <<= 1) {
        unsigned int v = __shfl_up(incl, d, 64);
        if (t >= d) incl += v;
      }
      unsigned int ex = incl - sum;
      s_pref[4*t]   = ex;
      s_pref[4*t+1] = ex + b0;
      s_pref[4*t+2] = ex + b0 + b1;
      s_pref[4*t+3] = ex + b0 + b1 + b2;
      if (t == 63) s_pref[256] = incl;
    }
    __syncthreads();
    // find bucket containing TR
    if (t < 256) {
      unsigned int lo = s_pref[t], hi = s_pref[t+1];
      if (lo <= TR && TR < hi) { s_info[0] = (unsigned)t; s_info[1] = lo; s_info[2] = hi - lo; }
    }
    __syncthreads();
    unsigned int b = s_info[0], lo = s_info[1], cnt = s_info[2];
    TR -= lo;
    prefVal = (prefVal << 8) | b;
    cshift = shift;
    if (cnt <= 256u || pass == 2) break;
    shift -= 8;
    __syncthreads();   // protect s_hist reuse
  }

  // ---- collect candidates: all keys with (key>>cshift) <= prefVal
  if (t == 0) s_info[3] = 0u;
  __syncthreads();
  #pragma unroll
  for (int s = 0; s < 16; ++s) {
    if ((unsigned int)(key[s] >> cshift) <= prefVal) {
      unsigned int pos = atomicAdd(&s_info[3], 1u);
      if (pos < 320u) { s_ck[pos] = key[s]; s_cj[pos] = t + s * 256; }
    }
  }
  __syncthreads();

  // ---- wave 0: barrier-free sorted extraction of 63 winners + outputs
  if (t < 64) {
    int m = (int)s_info[3]; if (m > 320) m = 320;
    unsigned long long ck[5]; int cj[5];
    #pragma unroll
    for (int r = 0; r < 5; ++r) {
      int slot = t + r * 64;
      if (slot < m) { ck[r] = s_ck[slot]; cj[r] = s_cj[slot]; }
      else          { ck[r] = INVALID;    cj[r] = 0x7FFFFFFF; }
    }
    unsigned long long myk = 0ull; int myj = i;   // k=0: self, d=0
    #pragma unroll 1
    for (int k = 1; k < 64; ++k) {
      unsigned long long bk = ck[0]; int bj = cj[0];
      #pragma unroll
      for (int r = 1; r < 5; ++r)
        if (ck[r] < bk || (ck[r] == bk && cj[r] < bj)) { bk = ck[r]; bj = cj[r]; }
      #pragma unroll
      for (int o = 32; o > 0; o >>= 1) {
        unsigned long long ok = __shfl_xor(bk, o, 64);
        int                oj = __shfl_xor(bj, o, 64);
        if (ok < bk || (ok == bk && oj < bj)) { bk = ok; bj = oj; }
      }
      if (t == k) { myk = bk; myj = bj; }
      #pragma unroll
      for (int r = 0; r < 5; ++r)
        if (ck[r] == bk && cj[r] == bj) ck[r] = INVALID;
    }
    // outputs
    double sq = __longlong_as_double((long long)myk);
    size_t base = (size_t)i * 64 + t;
    out_d[base]   = (float)sqrt(sq);
    out_idx[base] = (float)myj;
    idx_ws[base]  = myj;
    int off = i - myj; if (off < 0) off = -off;
    float offf = (float)off;
    float* pp = out_pos + base * 16;
    #pragma unroll
    for (int f = 0; f < 8; ++f) {
      float ang = offf * c_freq[f];
      pp[f]     = cosf(ang);
      pp[8 + f] = sinf(ang);
    }
  }
}

// ---------------- kernel 3: grbf distance features ------------------------
// One block per row i (4096 blocks): stage 64 pairs x 25 distances in LDS,
// then each wave writes its 16 pairs as 25 fully-dense rounds of coalesced
// float4 stores (100% lane utilization).
__global__ __launch_bounds__(256) void feat_kernel(
    const float* __restrict__ crd5,
    const int* __restrict__ idx_ws,
    float* __restrict__ out_dist,
    int N) {
  const int i = blockIdx.x;
  const int t = threadIdx.x;

  __shared__ int   s_nj[64];
  __shared__ float s_ci[15];
  __shared__ float s_d[64][25];

  if (t < 64) s_nj[t] = idx_ws[(size_t)i * 64 + t];
  if (t < 15) s_ci[t] = crd5[(size_t)i * 15 + t];
  __syncthreads();

  #pragma unroll
  for (int r = 0; r < 7; ++r) {
    int item = t + r * 256;           // 0..1599 = pair k * 25 + q
    if (item < 1600) {
      int k = item / 25, q = item - k * 25;
      int p = q / 5, a = q - p * 5;
      const float* B = crd5 + (size_t)s_nj[k] * 15 + a * 3;
      float dx = s_ci[p*3+0] - B[0];
      float dy = s_ci[p*3+1] - B[1];
      float dz = s_ci[p*3+2] - B[2];
      s_d[k][q] = sqrtf(dx*dx + dy*dy + dz*dz);
    }
  }
  __syncthreads();

  const int w = t >> 6, lane = t & 63;
  const float SC = 20.0f / 15.0f;
  float4* o = (float4*)out_dist + ((size_t)i * 64 + w * 16) * 100;
  #pragma unroll
  for (int r = 0; r < 25; ++r) {
    int local = lane + r * 64;            // 0..1599 within this wave's 16 pairs
    int p16 = local / 100, s = local - p16 * 100;
    float dd = s_d[w * 16 + p16][s >> 2];
    float c0 = (float)((s & 3) * 4) * SC;
    float x0 = dd - c0;                 float x1 = dd - (c0 + SC);
    float x2 = dd - (c0 + 2.0f * SC);   float x3 = dd - (c0 + 3.0f * SC);
    float4 v;
    v.x = __expf(-x0 * x0); v.y = __expf(-x1 * x1);
    v.z = __expf(-x2 * x2); v.w = __expf(-x3 * x3);
    o[local] = v;
  }
}

// ---------------- launcher ------------------------------------------------
extern "C" void kernel_launch(void* const* d_in, const int* in_sizes, int n_in,
                              void* d_out, int out_size, void* d_ws, size_t ws_size,
                              hipStream_t stream) {
  const float* crd = (const float*)d_in[0];
  const int N = in_sizes[0] / 12;        // 4096
  const size_t NK = (size_t)N * 64;

  // workspace: [ idx int NK | crd5 float N*15 ]
  int*   idx_ws = (int*)d_ws;
  float* crd5   = (float*)((char*)d_ws + NK * sizeof(int));

  float* out = (float*)d_out;
  float* out_d    = out;
  float* out_dist = out + NK;
  float* out_pos  = out + NK + NK * 400;
  float* out_idx  = out + NK + NK * 400 + NK * 16;

  crd5_kernel<<<(N + 255) / 256, 256, 0, stream>>>(crd, crd5, N);
  knn_kernel<<<N, 256, 0, stream>>>(crd, out_d, out_pos, out_idx, idx_ws, N);
  feat_kernel<<<N, 256, 0, stream>>>(crd5, idx_ws, out_dist, N);
}

// Round 8
// 553.832 us; speedup vs baseline: 1.3806x; 1.1340x over previous
//
#include <hip/hip_runtime.h>
#include <hip/hip_bf16.h>
#include <math.h>

// Outputs (float32, concatenated): d[N][64] | dist[N][64][400] | pos[N][64][16] | idx[N][64]
// N = 4096, K = 64 neighbors (self first). Ordering follows f64-exact
// squared distances (monotone u64 bit keys), tie-break lower index.

// freq[f] = 10^(-f/2)
__device__ __constant__ float c_freq[8] = {
  1.0f, 0.31622776601683794f, 0.1f, 0.031622776601683791f,
  0.01f, 0.0031622776601683794f, 0.001f, 0.00031622776601683794f
};

// ---------------- kernel 1: build crd5 = [crd(4 atoms), Cb] + packed ca ----
__global__ __launch_bounds__(256) void crd5_kernel(
    const float* __restrict__ crd, float* __restrict__ crd5,
    float4* __restrict__ ca4, int N) {
  int i = blockIdx.x * 256 + threadIdx.x;
  if (i >= N) return;
  const float* p = crd + (size_t)i * 12;
  float p0x=p[0], p0y=p[1], p0z=p[2];
  float p1x=p[3], p1y=p[4], p1z=p[5];
  float p2x=p[6], p2y=p[7], p2z=p[8];
  float p3x=p[9], p3y=p[10], p3z=p[11];
  float bx=__fsub_rn(p1x,p0x), by=__fsub_rn(p1y,p0y), bz=__fsub_rn(p1z,p0z);
  float cx=__fsub_rn(p2x,p1x), cy=__fsub_rn(p2y,p1y), cz=__fsub_rn(p2z,p1z);
  float ax=__fsub_rn(__fmul_rn(by,cz), __fmul_rn(bz,cy));
  float ay=__fsub_rn(__fmul_rn(bz,cx), __fmul_rn(bx,cz));
  float az=__fsub_rn(__fmul_rn(bx,cy), __fmul_rn(by,cx));
  const float K1 = -0.58273431f, K2 = 0.56802827f, K3 = 0.54067466f;
  float cbx=__fadd_rn(__fsub_rn(__fadd_rn(__fmul_rn(K1,ax),__fmul_rn(K2,bx)),__fmul_rn(K3,cx)),p1x);
  float cby=__fadd_rn(__fsub_rn(__fadd_rn(__fmul_rn(K1,ay),__fmul_rn(K2,by)),__fmul_rn(K3,cy)),p1y);
  float cbz=__fadd_rn(__fsub_rn(__fadd_rn(__fmul_rn(K1,az),__fmul_rn(K2,bz)),__fmul_rn(K3,cz)),p1z);
  float* o = crd5 + (size_t)i * 15;
  o[0]=p0x; o[1]=p0y; o[2]=p0z;
  o[3]=p1x; o[4]=p1y; o[5]=p1z;
  o[6]=p2x; o[7]=p2y; o[8]=p2z;
  o[9]=p3x; o[10]=p3y; o[11]=p3z;
  o[12]=cbx; o[13]=cby; o[14]=cbz;
  ca4[i] = make_float4(p1x, p1y, p1z, 0.0f);
}

// ---------------- kernel 2: kNN via radix-select + counting-rank -----------
// One 256-thread block per row i; thread t owns candidates j = t + s*256.
// 8-bit radix passes (bank-staggered [8][257] sub-histograms) locate the
// bucket holding the 63rd-smallest non-self key; candidates (<=320) are
// collected to LDS; every candidate's exact lexicographic (key,idx) rank is
// computed by parallel counting (O(m^2) broadcast LDS reads, no shuffles);
// rank r < 63 lands in output slot r+1. Identical order to lax.top_k.
__global__ __launch_bounds__(256) void knn_kernel(
    const float4* __restrict__ ca4,
    float* __restrict__ out_d,
    float* __restrict__ out_pos,
    float* __restrict__ out_idx,
    int* __restrict__ idx_ws,
    int N) {
  const int i = blockIdx.x;
  const int t = threadIdx.x;

  __shared__ unsigned int s_hist[8][257];     // bank-staggered sub-histograms
  __shared__ unsigned int s_pref[257];
  __shared__ unsigned int s_info[4];          // [0]=bucket [1]=lo [2]=cnt [3]=cand count
  __shared__ unsigned long long s_ck[320];
  __shared__ int                s_cj[320];
  __shared__ unsigned long long s_ok[64];
  __shared__ int                s_oj[64];

  const unsigned long long INVALID = 0xFFFFFFFFFFFFFFFFull;

  const float4 ci = ca4[i];
  const double cix = (double)ci.x, ciy = (double)ci.y, ciz = (double)ci.z;

  unsigned long long key[16];
  #pragma unroll
  for (int s = 0; s < 16; ++s) {
    int j = t + s * 256;
    unsigned long long kk = INVALID;
    if (j < N && j != i) {
      float4 cj = ca4[j];
      double dx = cix - (double)cj.x;
      double dy = ciy - (double)cj.y;
      double dz = ciz - (double)cj.z;
      double sq = dx*dx + dy*dy + dz*dz;
      kk = (unsigned long long)__double_as_longlong(sq);
    }
    key[s] = kk;
  }

  // ---- radix passes: find bucket containing rank-62 (0-based) non-self key
  unsigned int TR = 62;
  unsigned int prefVal = 0;
  int shift = 56;
  int cshift = 56;

  #pragma unroll 1
  for (int pass = 0; pass < 3; ++pass) {
    unsigned int* hflat = &s_hist[0][0];
    #pragma unroll
    for (int z = 0; z < 9; ++z) {
      int zi = t + z * 256;
      if (zi < 8 * 257) hflat[zi] = 0u;
    }
    __syncthreads();
    unsigned int* h = &s_hist[t >> 5][0];
    if (pass == 0) {
      #pragma unroll
      for (int s = 0; s < 16; ++s)
        if (key[s] != INVALID) atomicAdd(&h[(unsigned int)(key[s] >> 56)], 1u);
    } else {
      #pragma unroll
      for (int s = 0; s < 16; ++s)
        if ((unsigned int)(key[s] >> (shift + 8)) == prefVal)
          atomicAdd(&h[(unsigned int)(key[s] >> shift) & 255u], 1u);
    }
    __syncthreads();
    if (t < 256) {
      unsigned int v = 0;
      #pragma unroll
      for (int g = 0; g < 8; ++g) v += s_hist[g][t];
      s_hist[0][t] = v;
    }
    __syncthreads();
    // exclusive prefix over 256 bins (wave 0, 4 bins/lane)
    if (t < 64) {
      unsigned int b0 = s_hist[0][4*t], b1 = s_hist[0][4*t+1];
      unsigned int b2 = s_hist[0][4*t+2], b3 = s_hist[0][4*t+3];
      unsigned int sum = b0 + b1 + b2 + b3;
      unsigned int incl = sum;
      #pragma unroll
      for (int d = 1; d < 64; d <<= 1) {
        unsigned int v = __shfl_up(incl, d, 64);
        if (t >= d) incl += v;
      }
      unsigned int ex = incl - sum;
      s_pref[4*t]   = ex;
      s_pref[4*t+1] = ex + b0;
      s_pref[4*t+2] = ex + b0 + b1;
      s_pref[4*t+3] = ex + b0 + b1 + b2;
    }
    __syncthreads();
    if (t < 256) {
      unsigned int lo = s_pref[t];
      unsigned int hi = (t < 255) ? s_pref[t+1] : 0xFFFFFFFFu;
      if (lo <= TR && TR < hi) { s_info[0] = (unsigned)t; s_info[1] = lo; s_info[2] = hi - lo; }
    }
    __syncthreads();
    unsigned int b = s_info[0], lo = s_info[1], cnt = s_info[2];
    TR -= lo;
    prefVal = (prefVal << 8) | b;
    cshift = shift;
    if (cnt <= 256u || pass == 2) break;
    shift -= 8;
    __syncthreads();
  }

  // ---- collect candidates: all keys with (key>>cshift) <= prefVal
  if (t == 0) s_info[3] = 0u;
  __syncthreads();
  #pragma unroll
  for (int s = 0; s < 16; ++s) {
    if (key[s] != INVALID && (unsigned int)(key[s] >> cshift) <= prefVal) {
      unsigned int pos = atomicAdd(&s_info[3], 1u);
      if (pos < 320u) { s_ck[pos] = key[s]; s_cj[pos] = t + s * 256; }
    }
  }
  if (t == 0) { s_ok[0] = 0ull; s_oj[0] = i; }   // slot 0 = self, d = 0
  __syncthreads();

  // ---- counting-rank: each thread owns slots t and t+256
  int m = (int)s_info[3]; if (m > 320) m = 320;
  #pragma unroll
  for (int c = 0; c < 2; ++c) {
    int slot = t + c * 256;
    if (slot < m) {
      unsigned long long k0 = s_ck[slot]; int j0 = s_cj[slot];
      int rank = 0;
      #pragma unroll 4
      for (int x = 0; x < m; ++x) {
        unsigned long long kx = s_ck[x]; int jx = s_cj[x];
        if (kx < k0 || (kx == k0 && jx < j0)) ++rank;
      }
      if (rank < 63) { s_ok[rank + 1] = k0; s_oj[rank + 1] = j0; }
    }
  }
  __syncthreads();

  // ---- outputs (wave 0)
  if (t < 64) {
    unsigned long long myk = s_ok[t];
    int myj = s_oj[t];
    double sq = __longlong_as_double((long long)myk);
    size_t base = (size_t)i * 64 + t;
    out_d[base]   = (float)sqrt(sq);
    out_idx[base] = (float)myj;
    idx_ws[base]  = myj;
    int off = i - myj; if (off < 0) off = -off;
    float offf = (float)off;
    float* pp = out_pos + base * 16;
    #pragma unroll
    for (int f = 0; f < 8; ++f) {
      float ang = offf * c_freq[f];
      pp[f]     = cosf(ang);
      pp[8 + f] = sinf(ang);
    }
  }
}

// ---------------- kernel 3: grbf distance features ------------------------
// One block per row i (4096 blocks): stage 64 pairs x 25 distances in LDS,
// then each wave writes its 16 pairs as 25 fully-dense rounds of coalesced
// float4 stores.
__global__ __launch_bounds__(256) void feat_kernel(
    const float* __restrict__ crd5,
    const int* __restrict__ idx_ws,
    float* __restrict__ out_dist,
    int N) {
  const int i = blockIdx.x;
  const int t = threadIdx.x;

  __shared__ int   s_nj[64];
  __shared__ float s_ci[15];
  __shared__ float s_d[64][25];

  if (t < 64) s_nj[t] = idx_ws[(size_t)i * 64 + t];
  if (t < 15) s_ci[t] = crd5[(size_t)i * 15 + t];
  __syncthreads();

  #pragma unroll
  for (int r = 0; r < 7; ++r) {
    int item = t + r * 256;           // 0..1599 = pair k * 25 + q
    if (item < 1600) {
      int k = item / 25, q = item - k * 25;
      int p = q / 5, a = q - p * 5;
      const float* B = crd5 + (size_t)s_nj[k] * 15 + a * 3;
      float dx = s_ci[p*3+0] - B[0];
      float dy = s_ci[p*3+1] - B[1];
      float dz = s_ci[p*3+2] - B[2];
      s_d[k][q] = sqrtf(dx*dx + dy*dy + dz*dz);
    }
  }
  __syncthreads();

  const int w = t >> 6, lane = t & 63;
  const float SC = 20.0f / 15.0f;
  float4* o = (float4*)out_dist + ((size_t)i * 64 + w * 16) * 100;
  #pragma unroll
  for (int r = 0; r < 25; ++r) {
    int local = lane + r * 64;            // 0..1599 within this wave's 16 pairs
    int p16 = local / 100, s = local - p16 * 100;
    float dd = s_d[w * 16 + p16][s >> 2];
    float c0 = (float)((s & 3) * 4) * SC;
    float x0 = dd - c0;                 float x1 = dd - (c0 + SC);
    float x2 = dd - (c0 + 2.0f * SC);   float x3 = dd - (c0 + 3.0f * SC);
    float4 v;
    v.x = __expf(-x0 * x0); v.y = __expf(-x1 * x1);
    v.z = __expf(-x2 * x2); v.w = __expf(-x3 * x3);
    o[local] = v;
  }
}

// ---------------- launcher ------------------------------------------------
extern "C" void kernel_launch(void* const* d_in, const int* in_sizes, int n_in,
                              void* d_out, int out_size, void* d_ws, size_t ws_size,
                              hipStream_t stream) {
  const float* crd = (const float*)d_in[0];
  const int N = in_sizes[0] / 12;        // 4096
  const size_t NK = (size_t)N * 64;

  // workspace: [ ca4 float4 N | idx int NK | crd5 float N*15 ]
  float4* ca4   = (float4*)d_ws;
  int*    idx_ws = (int*)((char*)d_ws + (size_t)N * sizeof(float4));
  float*  crd5  = (float*)((char*)d_ws + (size_t)N * sizeof(float4) + NK * sizeof(int));

  float* out = (float*)d_out;
  float* out_d    = out;
  float* out_dist = out + NK;
  float* out_pos  = out + NK + NK * 400;
  float* out_idx  = out + NK + NK * 400 + NK * 16;

  crd5_kernel<<<(N + 255) / 256, 256, 0, stream>>>(crd, crd5, ca4, N);
  knn_kernel<<<N, 256, 0, stream>>>(ca4, out_d, out_pos, out_idx, idx_ws, N);
  feat_kernel<<<N, 256, 0, stream>>>(crd5, idx_ws, out_dist, N);
}